// Round 1
// baseline (11908.052 us; speedup 1.0000x reference)
//
#include <hip/hip_runtime.h>
#include <cstdint>
#include <cstddef>

#define T_STEPS 1024
#define BATCH   128
#define INF     128   // used input features (130 minus last 2)
#define HID     512
#define G4      2048  // 4*HID

// ---------------- init / transpose kernels (run once per call) ----------------

// xT[t][i][b] = inputs[b][t][i], i < 128  (drop last 2 features)
__global__ __launch_bounds__(256) void k_transpose_x(const float* __restrict__ in,
                                                     float* __restrict__ xT)
{
  int blk = blockIdx.x;            // t*4 + bg
  int t = blk >> 2, bg = blk & 3;
  __shared__ float tile[32][129];
  int tid = threadIdx.x;
  #pragma unroll
  for (int rep = 0; rep < 16; ++rep) {
    int idx = rep * 256 + tid;
    int bl = idx >> 7, i = idx & 127;
    tile[bl][i] = in[((size_t)(bg * 32 + bl) * T_STEPS + t) * 130 + i];
  }
  __syncthreads();
  #pragma unroll
  for (int rep = 0; rep < 16; ++rep) {
    int idx = rep * 256 + tid;
    int i = idx >> 5, bl = idx & 31;
    xT[((size_t)t * INF + i) * BATCH + bg * 32 + bl] = tile[bl][i];
  }
}

// WT[k][g]: k<128 -> W_ih[g][k], else W_hh[g][k-128]
__global__ __launch_bounds__(256) void k_transpose_w(const float* __restrict__ Wih,
                                                     const float* __restrict__ Whh,
                                                     float* __restrict__ WT)
{
  int k = blockIdx.x;  // 0..639
  for (int g = threadIdx.x; g < G4; g += 256) {
    float v = (k < INF) ? Wih[(size_t)g * INF + k] : Whh[(size_t)g * HID + (k - INF)];
    WT[(size_t)k * G4 + g] = v;
  }
}

// hbuf0[k][b] = h0[b][k]; cst[k][b] = c0[b][k]
__global__ __launch_bounds__(256) void k_init_state(const float* __restrict__ h0,
                                                    const float* __restrict__ c0,
                                                    float* __restrict__ hbuf0,
                                                    float* __restrict__ cst)
{
  int idx = blockIdx.x * 256 + threadIdx.x;   // 0 .. 512*128-1
  int k = idx >> 7, b = idx & 127;
  hbuf0[idx] = h0[(size_t)b * HID + k];
  cst[idx]   = c0[(size_t)b * HID + k];
}

// ---------------- one LSTM time step ----------------
// grid: 256 blocks = 64 unit-groups (8 units each) x 4 batch-groups (32 b each)
// block: 512 threads = 8 waves; wave w handles k-slice (16 x-k's + 64 h-k's)
// lane: 4 b x 4 gate-rows register tile
__global__ __launch_bounds__(512) void k_step(
    const float* __restrict__ xT,     // [T][128][128] (t,i,b)
    const float* __restrict__ WT,     // [640][2048]   (k,g)
    const float* __restrict__ bih, const float* __restrict__ bhh,
    const float* __restrict__ hprev,  // [512][128]    (k,b)
    float* __restrict__ hnext,        // [512][128]
    float* __restrict__ cst,          // [512][128]
    const int* __restrict__ len,
    float* __restrict__ out,          // [128][512]
    int t)
{
  int blk = blockIdx.x;
  int ug = blk & 63, bg = blk >> 6;
  int tid = threadIdx.x;
  int w = tid >> 6, l = tid & 63;
  int b4 = (l & 7) * 4;              // 0,4,...,28
  int r4 = (l >> 3) * 4;             // 0,4,...,28
  int q  = r4 >> 3, u0 = r4 & 7;     // rows r4..r4+3 share gate-type q, units u0..u0+3
  int g0 = q * HID + ug * 8 + u0;    // 4 consecutive global gate rows

  float acc[4][4] = {};

  // ---- x contribution: k in [w*16, w*16+16) ----
  const float* xt = xT + (size_t)t * INF * BATCH + bg * 32;
  #pragma unroll 4
  for (int k = w * 16; k < w * 16 + 16; ++k) {
    float4 xv = *(const float4*)(xt + (size_t)k * BATCH + b4);
    float4 wv = *(const float4*)(WT + (size_t)k * G4 + g0);
    float xa[4] = {xv.x, xv.y, xv.z, xv.w};
    float wa[4] = {wv.x, wv.y, wv.z, wv.w};
    #pragma unroll
    for (int i = 0; i < 4; ++i)
      #pragma unroll
      for (int j = 0; j < 4; ++j)
        acc[i][j] = fmaf(xa[i], wa[j], acc[i][j]);
  }

  // ---- h contribution: k in [w*64, w*64+64) ----
  const float* hp = hprev + bg * 32;
  #pragma unroll 4
  for (int k = w * 64; k < w * 64 + 64; ++k) {
    float4 hv = *(const float4*)(hp + (size_t)k * BATCH + b4);
    float4 wv = *(const float4*)(WT + (size_t)(INF + k) * G4 + g0);
    float ha[4] = {hv.x, hv.y, hv.z, hv.w};
    float wa[4] = {wv.x, wv.y, wv.z, wv.w};
    #pragma unroll
    for (int i = 0; i < 4; ++i)
      #pragma unroll
      for (int j = 0; j < 4; ++j)
        acc[i][j] = fmaf(ha[i], wa[j], acc[i][j]);
  }

  // ---- cross-wave reduction ----
  __shared__ float red[8][1024];
  #pragma unroll
  for (int j = 0; j < 4; ++j)
    #pragma unroll
    for (int i = 0; i < 4; ++i)
      red[w][(r4 + j) * 32 + (b4 + i)] = acc[i][j];
  __syncthreads();

  // ---- cell update: one thread per (b, unit) ----
  if (tid < 256) {
    int b = tid & 31, u = tid >> 5;          // b 0..31, u 0..7
    int gb = bg * 32 + b, hu = ug * 8 + u;
    float gate[4];
    #pragma unroll
    for (int qq = 0; qq < 4; ++qq) {
      int r = qq * 8 + u;
      float s = 0.f;
      #pragma unroll
      for (int ww = 0; ww < 8; ++ww) s += red[ww][r * 32 + b];
      int g = qq * HID + hu;
      gate[qq] = s + bih[g] + bhh[g];
    }
    float iv = 1.f / (1.f + expf(-gate[0]));
    float fv = 1.f / (1.f + expf(-gate[1]));
    float gv = tanhf(gate[2]);
    float ov = 1.f / (1.f + expf(-gate[3]));
    float c  = cst[(size_t)hu * BATCH + gb];
    float c2 = fv * c + iv * gv;
    float h2 = ov * tanhf(c2);
    cst[(size_t)hu * BATCH + gb]   = c2;
    hnext[(size_t)hu * BATCH + gb] = h2;
    if (t == len[gb] - 1) out[(size_t)gb * HID + hu] = h2;
  }
}

// ---------------- launch ----------------
extern "C" void kernel_launch(void* const* d_in, const int* in_sizes, int n_in,
                              void* d_out, int out_size, void* d_ws, size_t ws_size,
                              hipStream_t stream)
{
  const float* inputs = (const float*)d_in[0];
  const int*   len    = (const int*)  d_in[1];
  const float* h0     = (const float*)d_in[2];
  const float* c0     = (const float*)d_in[3];
  const float* Wih    = (const float*)d_in[4];
  const float* Whh    = (const float*)d_in[5];
  const float* bih    = (const float*)d_in[6];
  const float* bhh    = (const float*)d_in[7];
  float* out = (float*)d_out;

  char* p = (char*)d_ws;
  float* xT = (float*)p;  p += (size_t)T_STEPS * INF * BATCH * sizeof(float);  // 64 MB
  float* WT = (float*)p;  p += (size_t)(INF + HID) * G4 * sizeof(float);       // 5.25 MB
  float* hbuf0 = (float*)p; p += (size_t)HID * BATCH * sizeof(float);
  float* hbuf1 = (float*)p; p += (size_t)HID * BATCH * sizeof(float);
  float* cst   = (float*)p; p += (size_t)HID * BATCH * sizeof(float);
  float* hbuf[2] = {hbuf0, hbuf1};

  k_transpose_x<<<T_STEPS * 4, 256, 0, stream>>>(inputs, xT);
  k_transpose_w<<<INF + HID, 256, 0, stream>>>(Wih, Whh, WT);
  k_init_state<<<(HID * BATCH) / 256, 256, 0, stream>>>(h0, c0, hbuf[0], cst);

  for (int t = 0; t < T_STEPS; ++t) {
    k_step<<<256, 512, 0, stream>>>(xT, WT, bih, bhh,
                                    hbuf[t & 1], hbuf[(t + 1) & 1],
                                    cst, len, out, t);
  }
}